// Round 9
// baseline (331.268 us; speedup 1.0000x reference)
//
#include <hip/hip_runtime.h>
#include <hip/hip_bf16.h>
#include <math.h>

// Problem constants
#define Bn 8
#define Cn 64
#define Hn 128
#define Wn 128
#define Rn 4

typedef __bf16 v8bf __attribute__((ext_vector_type(8)));
typedef float  v16f __attribute__((ext_vector_type(16)));

__device__ __forceinline__ float leaky(float x) { return x >= 0.f ? x : 0.1f * x; }

__device__ __forceinline__ unsigned bf16pair(float a, float b) {
    __hip_bfloat16 ha = __float2bfloat16(a);
    __hip_bfloat16 hb = __float2bfloat16(b);
    return (unsigned)*reinterpret_cast<unsigned short*>(&ha) |
           ((unsigned)*reinterpret_cast<unsigned short*>(&hb) << 16);
}

// ---------------------------------------------------------------------------
// Kernel A: per-batch dynamic depthwise kernels + channel attn; block Bn
// converts w_conv -> bf16 [o][c].
//   kern_g[b][c][r][9]  (b*2304 + c*36 + r*9 + kk)
//   att_g [b][r][c]
// ---------------------------------------------------------------------------
__global__ __launch_bounds__(256) void precomp_kernel(
    const float* __restrict__ deg, const float* __restrict__ w_k1,
    const float* __restrict__ w_k2, const float* __restrict__ w_ca1,
    const float* __restrict__ w_ca2, const float* __restrict__ w_conv,
    float* __restrict__ kern_g, float* __restrict__ att_g,
    unsigned short* __restrict__ wbf)
{
    const int tid = threadIdx.x;
    if (blockIdx.x == Bn) {                       // w_conv -> bf16
        for (int f = tid; f < Cn * Cn; f += 256) {
            __hip_bfloat16 hx = __float2bfloat16(w_conv[f]);
            wbf[f] = *reinterpret_cast<unsigned short*>(&hx);
        }
        return;
    }
    const int b = blockIdx.x;
    __shared__ float y_s[64], a_s[64];
    if (tid < 64) {
        float sy = 0.f, sa = 0.f;
#pragma unroll 8
        for (int j = 0; j < 64; ++j) {
            float d = deg[b * 64 + j];
            sy += d * w_k1[tid * 64 + j];
            sa += d * w_ca1[tid * 64 + j];
        }
        y_s[tid] = leaky(sy);
        a_s[tid] = leaky(sa);
    }
    __syncthreads();
    for (int f = tid; f < Cn * Rn * 9; f += 256) {
        int c = f / 36;
        int j = f - c * 36;
        int r = j / 9;
        int kk = j - r * 9;
        int o = c * 9 + kk;
        const float* wp = &w_k2[(r * 576 + o) * 16];
        const float* yp = &y_s[r * 16];
        float s = 0.f;
#pragma unroll
        for (int i = 0; i < 16; ++i) s += yp[i] * wp[i];
        kern_g[b * 2304 + f] = s;
    }
    {
        int r = tid >> 6, o = tid & 63;
        const float* wp = &w_ca2[(r * 64 + o) * 16];
        const float* ap = &a_s[r * 16];
        float s = 0.f;
#pragma unroll
        for (int i = 0; i < 16; ++i) s += ap[i] * wp[i];
        att_g[b * 256 + tid] = 1.f / (1.f + expf(-s));
    }
}

// ---------------------------------------------------------------------------
// Main kernel: one block per (b,h) row, 256 threads = 4 waves, ONE barrier.
// Wave wv owns columns [32wv, 32wv+32); lane = (col, kh). Each thread
// computes the depthwise t for exactly the 32 channels its MFMA B-fragments
// need (Bf[ks] = channels 16ks+8kh+j of column wn) -- entirely in registers,
// no t_lds, no inter-wave dependency. Taps via width-32 shfl + 2-lane edge
// loads. Then 8 x mfma_f32_32x32x16_bf16 against wc_lds A-fragments and the
// fused epilogue (bias + x0*att[r2]).
// ---------------------------------------------------------------------------
__global__ __launch_bounds__(256, 4) void da_main(
    const float* __restrict__ x0, const float* __restrict__ q_map,
    const unsigned short* __restrict__ wbf, const float* __restrict__ b_conv,
    const float* __restrict__ w_g1, const float* __restrict__ b_g1,
    const float* __restrict__ w_g2, const float* __restrict__ b_g2,
    const float* __restrict__ kern_g, const float* __restrict__ att_g,
    float* __restrict__ out)
{
    __shared__ __align__(16) float kern_lds[Cn * 48];           // 12 KB
    __shared__ __align__(16) unsigned short wc_lds[8][Cn][8];   // 8 KB
    __shared__ float att_lds[Rn * 68];                          // 1.1 KB
    __shared__ float bias_lds[Cn];                              // 0.25 KB

    const int tid = threadIdx.x;
    const int ob = blockIdx.x;
    // XCD-aware swizzle: XCD i gets batch i (4 MB image == one L2).
    const int sb = ((ob & 7) << 7) | (ob >> 3);
    const int b = sb >> 7;
    const int h = sb & 127;

    const int lane = tid & 63;
    const int wv = tid >> 6;              // wave id = w-tile
    const int col = lane & 31;
    const int kh = lane >> 5;
    const int wn = wv * 32 + col;         // this thread's column (all phases)

    // ---- phase 0: staging ----
    for (int f = tid; f < Cn * Rn * 9; f += 256) {
        int c = f / 36;
        int j = f - c * 36;
        int r = j / 9;
        int kk = j - r * 9;
        kern_lds[c * 48 + r * 12 + kk] = kern_g[b * 2304 + f];
    }
    {   // wc subtiles: cq = (tid>>6)+4u, o = tid&63 -> conflict-free writes
#pragma unroll
        for (int u = 0; u < 2; ++u) {
            int cq = (tid >> 6) + 4 * u;
            int o = tid & 63;
            *(v8bf*)&wc_lds[cq][o][0] = *(const v8bf*)&wbf[o * 64 + cq * 8];
        }
    }
    att_lds[(tid >> 6) * 68 + (tid & 63)] = att_g[b * 256 + tid];
    if (tid < 64) bias_lds[tid] = b_conv[tid];

    // ---- per-thread region routing for column wn ----
    int r1, r2;
    {
        float qv[9];
#pragma unroll
        for (int dh = 0; dh < 3; ++dh) {
            int row = h - 1 + dh;
#pragma unroll
            for (int dw = 0; dw < 3; ++dw) {
                int cc = wn - 1 + dw;
                qv[dh * 3 + dw] = (row >= 0 && row < Hn && cc >= 0 && cc < Wn)
                                      ? q_map[(b * Hn + row) * Wn + cc] : 0.f;
            }
        }
        float best1 = -1e30f, best2 = -1e30f;
        r1 = 0; r2 = 0;
#pragma unroll
        for (int r = 0; r < Rn; ++r) {
            float s1 = b_g1[r], s2 = b_g2[r];
#pragma unroll
            for (int k = 0; k < 9; ++k) {
                s1 += qv[k] * w_g1[r * 9 + k];
                s2 += qv[k] * w_g2[r * 9 + k];
            }
            if (s1 > best1) { best1 = s1; r1 = r; }   // strict > == first argmax
            if (s2 > best2) { best2 = s2; r2 = r; }
        }
    }
    __syncthreads();

    // ---- depthwise conv straight into MFMA B-fragments (registers) ----
    const bool okm = (h > 0);
    const bool okp = (h < Hn - 1);
    const float* xbase = x0 + (size_t)(b * Cn) * Hn * Wn + h * Wn + wn;

    v8bf Bf[4];
#pragma unroll
    for (int ks = 0; ks < 4; ++ks) {
        float tt[8];
#pragma unroll
        for (int j = 0; j < 8; ++j) {
            const int c = 16 * ks + 8 * kh + j;       // fragment channel
            const float* xc = xbase + c * (Hn * Wn);
            float vm = okm ? xc[-Wn] : 0.f;
            float v0 = xc[0];
            float vp = okp ? xc[Wn] : 0.f;
            float lm = __shfl_up(vm, 1, 32), l0 = __shfl_up(v0, 1, 32), lp = __shfl_up(vp, 1, 32);
            float rm = __shfl_down(vm, 1, 32), r0 = __shfl_down(v0, 1, 32), rp = __shfl_down(vp, 1, 32);
            if (col == 0) {                // left edge of this wave's 32-col tile
                if (wn == 0) { lm = 0.f; l0 = 0.f; lp = 0.f; }
                else { lm = okm ? xc[-1 - Wn] : 0.f; l0 = xc[-1]; lp = okp ? xc[-1 + Wn] : 0.f; }
            }
            if (col == 31) {               // right edge
                if (wn == 127) { rm = 0.f; r0 = 0.f; rp = 0.f; }
                else { rm = okm ? xc[1 - Wn] : 0.f; r0 = xc[1]; rp = okp ? xc[1 + Wn] : 0.f; }
            }
            const float* kp = &kern_lds[c * 48 + r1 * 12];   // 4-addr multicast
            float4 k03 = *(const float4*)kp;
            float4 k47 = *(const float4*)(kp + 4);
            float k8 = kp[8];
            float t = lm * k03.x + vm * k03.y + rm * k03.z
                    + l0 * k03.w + v0 * k47.x + r0 * k47.y
                    + lp * k47.z + vp * k47.w + rp * k8;
            tt[j] = leaky(t);
        }
        uint4 pk;
        pk.x = bf16pair(tt[0], tt[1]);
        pk.y = bf16pair(tt[2], tt[3]);
        pk.z = bf16pair(tt[4], tt[5]);
        pk.w = bf16pair(tt[6], tt[7]);
        Bf[ks] = __builtin_bit_cast(v8bf, pk);
    }

    // ---- MFMA channel mix ----
    v16f acc0, acc1;
#pragma unroll
    for (int i = 0; i < 16; ++i) { acc0[i] = 0.f; acc1[i] = 0.f; }

#pragma unroll
    for (int ks = 0; ks < 4; ++ks) {
        const int cq = 2 * ks + kh;
        v8bf A0 = *(const v8bf*)&wc_lds[cq][col][0];        // rows 0..31
        acc0 = __builtin_amdgcn_mfma_f32_32x32x16_bf16(A0, Bf[ks], acc0, 0, 0, 0);
        v8bf A1 = *(const v8bf*)&wc_lds[cq][32 + col][0];   // rows 32..63
        acc1 = __builtin_amdgcn_mfma_f32_32x32x16_bf16(A1, Bf[ks], acc1, 0, 0, 0);
    }

    // ---- fused epilogue: bias + x0*att[r2], coalesced stores ----
    const float* xcol = x0 + ((size_t)(b * Cn) * Hn + h) * Wn + wn;
    float* ocol = out + ((size_t)(b * Cn) * Hn + h) * Wn + wn;

#pragma unroll
    for (int r = 0; r < 16; ++r) {
        int row = (r & 3) + 8 * (r >> 2) + 4 * kh;
        float xv = xcol[(size_t)row * (Hn * Wn)];
        float res = acc0[r] + bias_lds[row] + xv * att_lds[r2 * 68 + row];
        ocol[(size_t)row * (Hn * Wn)] = res;
    }
#pragma unroll
    for (int r = 0; r < 16; ++r) {
        int row = 32 + (r & 3) + 8 * (r >> 2) + 4 * kh;
        float xv = xcol[(size_t)row * (Hn * Wn)];
        float res = acc1[r] + bias_lds[row] + xv * att_lds[r2 * 68 + row];
        ocol[(size_t)row * (Hn * Wn)] = res;
    }
}

// ---------------------------------------------------------------------------
extern "C" void kernel_launch(void* const* d_in, const int* in_sizes, int n_in,
                              void* d_out, int out_size, void* d_ws, size_t ws_size,
                              hipStream_t stream)
{
    const float* x0     = (const float*)d_in[0];
    const float* deg    = (const float*)d_in[1];
    const float* q_map  = (const float*)d_in[2];
    const float* w_k1   = (const float*)d_in[3];
    const float* w_k2   = (const float*)d_in[4];
    const float* w_conv = (const float*)d_in[5];
    const float* b_conv = (const float*)d_in[6];
    const float* w_ca1  = (const float*)d_in[7];
    const float* w_ca2  = (const float*)d_in[8];
    const float* w_g1   = (const float*)d_in[9];
    const float* b_g1   = (const float*)d_in[10];
    const float* w_g2   = (const float*)d_in[11];
    const float* b_g2   = (const float*)d_in[12];
    float* outp   = (float*)d_out;
    float* kern_g = (float*)d_ws;                           // 8*2304 floats
    float* att_g  = kern_g + Bn * Cn * Rn * 9;              // 8*256 floats
    unsigned short* wbf = (unsigned short*)(att_g + Bn * 256);  // 4096 bf16

    precomp_kernel<<<Bn + 1, 256, 0, stream>>>(deg, w_k1, w_k2, w_ca1, w_ca2,
                                               w_conv, kern_g, att_g, wbf);
    da_main<<<Bn * Hn, 256, 0, stream>>>(x0, q_map, wbf, b_conv,
                                         w_g1, b_g1, w_g2, b_g2,
                                         kern_g, att_g, outp);
}

// Round 10
// 43.912 us; speedup vs baseline: 7.5439x; 7.5439x over previous
//
#include <hip/hip_runtime.h>
#include <hip/hip_bf16.h>
#include <math.h>

// Problem constants
#define Bn 8
#define Cn 64
#define Hn 128
#define Wn 128
#define Rn 4

typedef __bf16 v8bf __attribute__((ext_vector_type(8)));
typedef float  v16f __attribute__((ext_vector_type(16)));

__device__ __forceinline__ float leaky(float x) { return x >= 0.f ? x : 0.1f * x; }

__device__ __forceinline__ unsigned bf16pair(float a, float b) {
    __hip_bfloat16 ha = __float2bfloat16(a);
    __hip_bfloat16 hb = __float2bfloat16(b);
    return (unsigned)*reinterpret_cast<unsigned short*>(&ha) |
           ((unsigned)*reinterpret_cast<unsigned short*>(&hb) << 16);
}

// ---------------------------------------------------------------------------
// Kernel A: per-batch dynamic depthwise kernels + channel attn; block Bn
// converts w_conv -> bf16 [o][c].
//   kern_g[b][c][r][9]  (b*2304 + c*36 + r*9 + kk)
//   att_g [b][r][c]
// ---------------------------------------------------------------------------
__global__ __launch_bounds__(256) void precomp_kernel(
    const float* __restrict__ deg, const float* __restrict__ w_k1,
    const float* __restrict__ w_k2, const float* __restrict__ w_ca1,
    const float* __restrict__ w_ca2, const float* __restrict__ w_conv,
    float* __restrict__ kern_g, float* __restrict__ att_g,
    unsigned short* __restrict__ wbf)
{
    const int tid = threadIdx.x;
    if (blockIdx.x == Bn) {                       // w_conv -> bf16
        for (int f = tid; f < Cn * Cn; f += 256) {
            __hip_bfloat16 hx = __float2bfloat16(w_conv[f]);
            wbf[f] = *reinterpret_cast<unsigned short*>(&hx);
        }
        return;
    }
    const int b = blockIdx.x;
    __shared__ float y_s[64], a_s[64];
    if (tid < 64) {
        float sy = 0.f, sa = 0.f;
#pragma unroll 8
        for (int j = 0; j < 64; ++j) {
            float d = deg[b * 64 + j];
            sy += d * w_k1[tid * 64 + j];
            sa += d * w_ca1[tid * 64 + j];
        }
        y_s[tid] = leaky(sy);
        a_s[tid] = leaky(sa);
    }
    __syncthreads();
    for (int f = tid; f < Cn * Rn * 9; f += 256) {
        int c = f / 36;
        int j = f - c * 36;
        int r = j / 9;
        int kk = j - r * 9;
        int o = c * 9 + kk;
        const float* wp = &w_k2[(r * 576 + o) * 16];
        const float* yp = &y_s[r * 16];
        float s = 0.f;
#pragma unroll
        for (int i = 0; i < 16; ++i) s += yp[i] * wp[i];
        kern_g[b * 2304 + f] = s;
    }
    {
        int r = tid >> 6, o = tid & 63;
        const float* wp = &w_ca2[(r * 64 + o) * 16];
        const float* ap = &a_s[r * 16];
        float s = 0.f;
#pragma unroll
        for (int i = 0; i < 16; ++i) s += ap[i] * wp[i];
        att_g[b * 256 + tid] = 1.f / (1.f + expf(-s));
    }
}

// ---------------------------------------------------------------------------
// Main kernel: one block per (b,h) row, 512 threads = 8 waves, 2 barriers.
// Same per-block work as R5 but spread over 2x the waves:
// Phase 1: thread (w = tid&127, q = tid>>7) computes t[c][w] for the 16
//          channels c in [16q,16q+16) (R5's pair loop: 3 coalesced loads +
//          6 shfl per channel, XOR-swizzled b32 pair writes).
// Phase 2: wave v = (oh, wt) computes the 32x32 tile out[32oh..][32wt..]
//          via 4 x mfma_f32_32x32x16_bf16 (acc = 16 f32, half of R5);
//          epilogue fuses bias + x0*att[r2].
// No forced min-waves bound: allocator free (R5 measured 60 VGPR; per-thread
// state here is smaller). VGPR<=64 -> 8 waves/SIMD, grid fully co-resident.
// ---------------------------------------------------------------------------
__global__ __launch_bounds__(512) void da_main(
    const float* __restrict__ x0, const float* __restrict__ q_map,
    const unsigned short* __restrict__ wbf, const float* __restrict__ b_conv,
    const float* __restrict__ w_g1, const float* __restrict__ b_g1,
    const float* __restrict__ w_g2, const float* __restrict__ b_g2,
    const float* __restrict__ kern_g, const float* __restrict__ att_g,
    float* __restrict__ out)
{
    __shared__ __align__(16) float kern_lds[Cn * 48];           // 12 KB
    __shared__ __align__(16) unsigned short wc_lds[8][Cn][8];   // 8 KB
    __shared__ __align__(16) unsigned short t_lds[Wn * Cn];     // 16 KB (XOR-swizzled [w][c])
    __shared__ float att_lds[Rn * 68];                          // 1.1 KB
    __shared__ float bias_lds[Cn];                              // 0.25 KB
    __shared__ int   ridx2[Wn];                                 // 0.5 KB

    const int tid = threadIdx.x;
    const int ob = blockIdx.x;
    // XCD-aware swizzle: XCD i gets batch i (4 MB image == one L2).
    const int sb = ((ob & 7) << 7) | (ob >> 3);
    const int b = sb >> 7;
    const int h = sb & 127;

    const int lane = tid & 63;
    const int w = tid & 127;
    const int q = tid >> 7;               // channel quarter: [16q, 16q+16)

    // ---- phase 0: staging ----
    for (int f = tid; f < Cn * Rn * 9; f += 512) {
        int c = f / 36;
        int j = f - c * 36;
        int r = j / 9;
        int kk = j - r * 9;
        kern_lds[c * 48 + r * 12 + kk] = kern_g[b * 2304 + f];
    }
    {   // wc subtiles: one conflict-free b128 write per thread
        int cq = tid & 7, o = tid >> 3;
        *(v8bf*)&wc_lds[cq][o][0] = *(const v8bf*)&wbf[o * 64 + cq * 8];
    }
    if (tid < 256) att_lds[(tid >> 6) * 68 + (tid & 63)] = att_g[b * 256 + tid];
    if (tid < 64) bias_lds[tid] = b_conv[tid];

    // region routing for this thread's column w (q == 0 publishes r2)
    int r1;
    {
        float qv[9];
#pragma unroll
        for (int dh = 0; dh < 3; ++dh) {
            int row = h - 1 + dh;
#pragma unroll
            for (int dw = 0; dw < 3; ++dw) {
                int col = w - 1 + dw;
                qv[dh * 3 + dw] = (row >= 0 && row < Hn && col >= 0 && col < Wn)
                                      ? q_map[(b * Hn + row) * Wn + col] : 0.f;
            }
        }
        float best1 = -1e30f, best2 = -1e30f;
        int r2 = 0; r1 = 0;
#pragma unroll
        for (int r = 0; r < Rn; ++r) {
            float s1 = b_g1[r], s2 = b_g2[r];
#pragma unroll
            for (int k = 0; k < 9; ++k) {
                s1 += qv[k] * w_g1[r * 9 + k];
                s2 += qv[k] * w_g2[r * 9 + k];
            }
            if (s1 > best1) { best1 = s1; r1 = r; }   // strict > == first argmax
            if (s2 > best2) { best2 = s2; r2 = r; }
        }
        if (q == 0) ridx2[w] = r2;
    }
    __syncthreads();

    // ---- phase 1: depthwise conv, 16 channels/thread (8 pairs) ----
    const bool okm = (h > 0);
    const bool okp = (h < Hn - 1);
    const float* xbase = x0 + (size_t)(b * Cn) * Hn * Wn + h * Wn + w;
    const int swz = (w & 7) << 4;

#pragma unroll 4
    for (int p = 0; p < 8; ++p) {                  // pairs of channels
        float tt[2];
#pragma unroll
        for (int u = 0; u < 2; ++u) {
            const int c = q * 16 + p * 2 + u;
            const float* xc = xbase + c * (Hn * Wn);
            float vm = okm ? xc[-Wn] : 0.f;
            float v0 = xc[0];
            float vp = okp ? xc[Wn] : 0.f;
            float lm = __shfl_up(vm, 1), l0 = __shfl_up(v0, 1), lp = __shfl_up(vp, 1);
            float rm = __shfl_down(vm, 1), r0 = __shfl_down(v0, 1), rp = __shfl_down(vp, 1);
            if (lane == 0) {
                if (w == 0) { lm = 0.f; l0 = 0.f; lp = 0.f; }
                else { lm = okm ? xc[-1 - Wn] : 0.f; l0 = xc[-1]; lp = okp ? xc[-1 + Wn] : 0.f; }
            }
            if (lane == 63) {
                if (w == 127) { rm = 0.f; r0 = 0.f; rp = 0.f; }
                else { rm = okm ? xc[1 - Wn] : 0.f; r0 = xc[1]; rp = okp ? xc[1 + Wn] : 0.f; }
            }
            const float* kp = &kern_lds[c * 48 + r1 * 12];   // 4-addr multicast
            float4 k03 = *(const float4*)kp;
            float4 k47 = *(const float4*)(kp + 4);
            float k8 = kp[8];
            float t = lm * k03.x + vm * k03.y + rm * k03.z
                    + l0 * k03.w + v0 * k47.x + r0 * k47.y
                    + lp * k47.z + vp * k47.w + rp * k8;
            tt[u] = leaky(t);
        }
        unsigned pk = bf16pair(tt[0], tt[1]);
        int cbyte = (q * 16 + p * 2) * 2;
        *(unsigned*)((char*)t_lds + w * 128 + (cbyte ^ swz)) = pk;
    }
    __syncthreads();

    // ---- phase 2: MFMA channel mix + fused epilogue ----
    const int v = tid >> 6;               // wave 0..7
    const int wt = v & 3;                 // w-tile (32 cols)
    const int oh = v >> 2;                // o-half (32 rows)
    const int col = lane & 31;
    const int kh = lane >> 5;
    const int wn = wt * 32 + col;         // this lane's output column

    v8bf Bf[4];
#pragma unroll
    for (int ks = 0; ks < 4; ++ks) {
        int cbyte = (16 * ks + 8 * kh) * 2;
        Bf[ks] = *(const v8bf*)((const char*)t_lds + wn * 128 + (cbyte ^ ((wn & 7) << 4)));
    }

    v16f acc;
#pragma unroll
    for (int i = 0; i < 16; ++i) acc[i] = 0.f;

#pragma unroll
    for (int ks = 0; ks < 4; ++ks) {
        const int cq = 2 * ks + kh;
        v8bf Af = *(const v8bf*)&wc_lds[cq][oh * 32 + col][0];
        acc = __builtin_amdgcn_mfma_f32_32x32x16_bf16(Af, Bf[ks], acc, 0, 0, 0);
    }

    const int r2e = ridx2[wn];
    const float* xcol = x0 + ((size_t)(b * Cn + oh * 32) * Hn + h) * Wn + wn;
    float* ocol = out + ((size_t)(b * Cn + oh * 32) * Hn + h) * Wn + wn;

#pragma unroll
    for (int r = 0; r < 16; ++r) {
        int row = (r & 3) + 8 * (r >> 2) + 4 * kh;     // 0..31 within tile
        int o = oh * 32 + row;
        float xv = xcol[(size_t)row * (Hn * Wn)];      // L2 hit
        float res = acc[r] + bias_lds[o] + xv * att_lds[r2e * 68 + o];
        ocol[(size_t)row * (Hn * Wn)] = res;           // 128B coalesced
    }
}

// ---------------------------------------------------------------------------
extern "C" void kernel_launch(void* const* d_in, const int* in_sizes, int n_in,
                              void* d_out, int out_size, void* d_ws, size_t ws_size,
                              hipStream_t stream)
{
    const float* x0     = (const float*)d_in[0];
    const float* deg    = (const float*)d_in[1];
    const float* q_map  = (const float*)d_in[2];
    const float* w_k1   = (const float*)d_in[3];
    const float* w_k2   = (const float*)d_in[4];
    const float* w_conv = (const float*)d_in[5];
    const float* b_conv = (const float*)d_in[6];
    const float* w_ca1  = (const float*)d_in[7];
    const float* w_ca2  = (const float*)d_in[8];
    const float* w_g1   = (const float*)d_in[9];
    const float* b_g1   = (const float*)d_in[10];
    const float* w_g2   = (const float*)d_in[11];
    const float* b_g2   = (const float*)d_in[12];
    float* outp   = (float*)d_out;
    float* kern_g = (float*)d_ws;                           // 8*2304 floats
    float* att_g  = kern_g + Bn * Cn * Rn * 9;              // 8*256 floats
    unsigned short* wbf = (unsigned short*)(att_g + Bn * 256);  // 4096 bf16

    precomp_kernel<<<Bn + 1, 256, 0, stream>>>(deg, w_k1, w_k2, w_ca1, w_ca2,
                                               w_conv, kern_g, att_g, wbf);
    da_main<<<Bn * Hn, 512, 0, stream>>>(x0, q_map, wbf, b_conv,
                                         w_g1, b_g1, w_g2, b_g2,
                                         kern_g, att_g, outp);
}